// Round 16
// baseline (465.840 us; speedup 1.0000x reference)
//
#include <hip/hip_runtime.h>
#include <math.h>

#define DM 128
#define DI 256
#define DSN 64
#define NB 8
#define LSEQ 4096
#define NTOK (NB*LSEQ)
#define GRP 4
#define GLEN (LSEQ/GRP)   // 1024

typedef float4 f4;
typedef __attribute__((ext_vector_type(8))) short bf16x8;
typedef __attribute__((ext_vector_type(4))) float f32x4;
typedef __attribute__((ext_vector_type(8))) unsigned short us8;

#if __has_builtin(__builtin_amdgcn_exp2f)
#define EXP2(x) __builtin_amdgcn_exp2f(x)
#else
#define EXP2(x) __expf((x)*0.6931471805599453f)
#endif

__device__ __forceinline__ float sigmoidf_(float x){ return 1.f/(1.f+__expf(-x)); }
__device__ __forceinline__ unsigned short f2bf(float f){
    unsigned u = __float_as_uint(f);
    unsigned r = u + 0x7FFFu + ((u>>16)&1u);   // RNE
    return (unsigned short)(r>>16);
}
__device__ __forceinline__ float bf2f(unsigned short s){
    return __uint_as_float(((unsigned)s)<<16);
}

// ---------------- LayerNorm stats (mu, rstd) per token ----------------
__global__ void __launch_bounds__(256) k_lnstats(const float* __restrict__ x, float* __restrict__ stats){
    int tok = blockIdx.x*4 + (threadIdx.x>>6);
    int lane = threadIdx.x & 63;
    const float* row = x + (size_t)tok*DM;
    float a = row[lane], b = row[lane+64];
    float s = a+b, ss = a*a+b*b;
    #pragma unroll
    for (int off=32; off>0; off>>=1){ s += __shfl_xor(s,off); ss += __shfl_xor(ss,off); }
    if (lane==0){
        float mu = s*(1.f/128.f);
        float var = ss*(1.f/128.f) - mu*mu;
        stats[tok*2+0] = mu;
        stats[tok*2+1] = rsqrtf(var + 1e-6f);
    }
}

// ---------------- bf16 MFMA GEMM: C[M][N] = A[M][K] * Bw[N][K]^T ----------------
// MODE 0: A = LN(x) on the fly; epilogue: col<256 -> Cout (xu fp32), col>=256 -> Zout (zbf bf16)
// MODE 1: A = fp32 row-major (x_proj); col<8 -> Cout2 (dt), cols 8..135 -> Cout (bc pack)
// MODE 2: A = bf16 row-major (out_proj, A=ygbf) + residual
template<int N_DIM,int K_DIM,int MODE>
__global__ void __launch_bounds__(256) k_gemm_bf(const float* __restrict__ Af32,
    const unsigned short* __restrict__ Abf, const float* __restrict__ Bw,
    float* __restrict__ Cout, float* __restrict__ Cout2, unsigned short* __restrict__ Zout,
    int ldC, const float* __restrict__ stats, const float* __restrict__ nw,
    const float* __restrict__ nb, const float* __restrict__ resid)
{
    __shared__ unsigned short Abuf[128*72];
    __shared__ unsigned short Bbuf[64*72];
    const int tid = threadIdx.x;
    const int m0 = blockIdx.x*128;
    const int n0 = blockIdx.y*64;
    const int wave = tid>>6, lane = tid&63;
    const int wm = wave>>1, wn = wave&1;
    const int lr = lane&15, lk = (lane>>4)*8;
    f32x4 acc[4][2];
    #pragma unroll
    for (int i=0;i<4;++i){
        #pragma unroll
        for (int j=0;j<2;++j) acc[i][j] = (f32x4){0.f,0.f,0.f,0.f};
    }

    for (int k0=0; k0<K_DIM; k0+=64){
        {
            int row = tid>>1, ks = (tid&1)*32;
            int m = m0 + row;
            unsigned short* dst = &Abuf[row*72 + ks];
            if (MODE==2){
                const unsigned short* src = Abf + (size_t)m*K_DIM + k0 + ks;
                #pragma unroll
                for (int q=0;q<4;++q) *(us8*)(dst+q*8) = *(const us8*)(src+q*8);
            } else {
                const float* src = Af32 + (size_t)m*K_DIM + k0 + ks;
                float mu=0.f, rs=1.f;
                if (MODE==0){ mu = stats[2*m]; rs = stats[2*m+1]; }
                #pragma unroll
                for (int q=0;q<4;++q){
                    f4 v0 = *(const f4*)(src+q*8);
                    f4 v1 = *(const f4*)(src+q*8+4);
                    if (MODE==0){
                        int kk = k0+ks+q*8;
                        f4 w0=*(const f4*)(nw+kk), w1=*(const f4*)(nw+kk+4);
                        f4 c0=*(const f4*)(nb+kk), c1=*(const f4*)(nb+kk+4);
                        v0.x=(v0.x-mu)*rs*w0.x+c0.x; v0.y=(v0.y-mu)*rs*w0.y+c0.y;
                        v0.z=(v0.z-mu)*rs*w0.z+c0.z; v0.w=(v0.w-mu)*rs*w0.w+c0.w;
                        v1.x=(v1.x-mu)*rs*w1.x+c1.x; v1.y=(v1.y-mu)*rs*w1.y+c1.y;
                        v1.z=(v1.z-mu)*rs*w1.z+c1.z; v1.w=(v1.w-mu)*rs*w1.w+c1.w;
                    }
                    us8 o = {f2bf(v0.x),f2bf(v0.y),f2bf(v0.z),f2bf(v0.w),
                             f2bf(v1.x),f2bf(v1.y),f2bf(v1.z),f2bf(v1.w)};
                    *(us8*)(dst+q*8) = o;
                }
            }
        }
        {
            int row = tid>>2, ks = (tid&3)*16;
            int n = n0 + row;
            unsigned short* dst = &Bbuf[row*72 + ks];
            #pragma unroll
            for (int q=0;q<2;++q){
                f4 v0={0.f,0.f,0.f,0.f}, v1={0.f,0.f,0.f,0.f};
                if (N_DIM%64==0 || n < N_DIM){
                    const float* src = Bw + (size_t)n*K_DIM + k0 + ks + q*8;
                    v0 = *(const f4*)src; v1 = *(const f4*)(src+4);
                }
                us8 o = {f2bf(v0.x),f2bf(v0.y),f2bf(v0.z),f2bf(v0.w),
                         f2bf(v1.x),f2bf(v1.y),f2bf(v1.z),f2bf(v1.w)};
                *(us8*)(dst+q*8) = o;
            }
        }
        __syncthreads();
        #pragma unroll
        for (int kk=0; kk<64; kk+=32){
            bf16x8 bfr[2], afr[4];
            #pragma unroll
            for (int fn=0;fn<2;++fn)
                bfr[fn] = *(const bf16x8*)&Bbuf[(wn*32+fn*16+lr)*72 + kk + lk];
            #pragma unroll
            for (int fm=0;fm<4;++fm)
                afr[fm] = *(const bf16x8*)&Abuf[(wm*64+fm*16+lr)*72 + kk + lk];
            #pragma unroll
            for (int fm=0;fm<4;++fm){
                #pragma unroll
                for (int fn=0;fn<2;++fn)
                    acc[fm][fn] = __builtin_amdgcn_mfma_f32_16x16x32_bf16(afr[fm], bfr[fn], acc[fm][fn], 0,0,0);
            }
        }
        __syncthreads();
    }
    const int cb = (lane>>4)*4;
    #pragma unroll
    for (int fm=0;fm<4;++fm){
        #pragma unroll
        for (int fn=0;fn<2;++fn){
            int col = n0 + wn*32 + fn*16 + lr;
            if (N_DIM%64!=0 && col >= N_DIM) continue;
            #pragma unroll
            for (int r=0;r<4;++r){
                int m = m0 + wm*64 + fm*16 + cb + r;
                float v = acc[fm][fn][r];
                if (MODE==0){
                    if (col < 256) Cout[(size_t)m*256 + col] = v;
                    else           Zout[(size_t)m*256 + (col-256)] = f2bf(v);
                } else if (MODE==1){
                    if (col < 8) Cout2[(size_t)m*8 + col] = v;
                    else         Cout[(size_t)m*128 + (col-8)] = v;
                } else {
                    v += resid[(size_t)m*N_DIM + col];
                    Cout[(size_t)m*ldC + col] = v;
                }
            }
        }
    }
}

// ---------------- transpose + gate: ygbf = bf16( ygT^T * silu(z) ), z in bf16 ----------------
__global__ void __launch_bounds__(256) k_trans(const float* __restrict__ ygT,
    const unsigned short* __restrict__ zbf, unsigned short* __restrict__ ygbf)
{
    __shared__ float T[64][65];
    int t0 = blockIdx.x*64;
    int w  = blockIdx.y;
    int b  = w>>2, d0 = (w&3)*64;
    int tid = threadIdx.x;
    {
        int dl = tid>>2, ts = (tid&3)*16;
        const float* src = ygT + ((size_t)(b*DI + d0 + dl))*LSEQ + t0 + ts;
        #pragma unroll
        for (int q=0;q<4;++q) *(f4*)&T[dl][ts+q*4] = *(const f4*)(src+q*4);
    }
    __syncthreads();
    {
        int tl = tid>>2, ds8 = (tid&3)*16;
        size_t tok = (size_t)(b*LSEQ + t0 + tl);
        const unsigned short* zsrc = zbf + tok*DI + d0 + ds8;
        unsigned short* dst = ygbf + tok*DI + d0 + ds8;
        us8 zv0 = *(const us8*)zsrc;
        us8 zv1 = *(const us8*)(zsrc+8);
        us8 o0, o1;
        #pragma unroll
        for (int j=0;j<8;++j){
            float z0 = bf2f(zv0[j]);
            float z1 = bf2f(zv1[j]);
            float g0 = z0 * sigmoidf_(z0);
            float g1 = z1 * sigmoidf_(z1);
            o0[j] = f2bf(T[ds8+j][tl]   * g0);
            o1[j] = f2bf(T[ds8+8+j][tl] * g1);
        }
        *(us8*)dst = o0; *(us8*)(dst+8) = o1;
    }
}

// ---------------- causal depthwise conv (k=4) + SiLU (reads compact xu) ----------------
__global__ void __launch_bounds__(256) k_conv(const float* __restrict__ xu,
    const float* __restrict__ cw, const float* __restrict__ cb, float* __restrict__ u)
{
    int idx = blockIdx.x*256 + threadIdx.x;
    int dq = idx & 63;
    int tok = idx >> 6;
    int t = tok & (LSEQ-1);
    f4 w0 = *(const f4*)(cw + (dq*4+0)*4);
    f4 w1 = *(const f4*)(cw + (dq*4+1)*4);
    f4 w2 = *(const f4*)(cw + (dq*4+2)*4);
    f4 w3 = *(const f4*)(cw + (dq*4+3)*4);
    f4 r  = *(const f4*)(cb + dq*4);
    #pragma unroll
    for (int j=0;j<4;++j){
        int tj = t-3+j;
        if (tj < 0) continue;
        f4 v = *(const f4*)(xu + (size_t)(tok-3+j)*DI + dq*4);
        r.x = fmaf(v.x, ((const float*)&w0)[j], r.x);
        r.y = fmaf(v.y, ((const float*)&w1)[j], r.y);
        r.z = fmaf(v.z, ((const float*)&w2)[j], r.z);
        r.w = fmaf(v.w, ((const float*)&w3)[j], r.w);
    }
    r.x *= sigmoidf_(r.x); r.y *= sigmoidf_(r.y);
    r.z *= sigmoidf_(r.z); r.w *= sigmoidf_(r.w);
    *(f4*)(u + (size_t)tok*DI + dq*4) = r;
}

// ---------------- delta = softplus(dt @ Wdt^T + bdt) ----------------
__global__ void __launch_bounds__(256) k_delta(const float* __restrict__ dt_c,
    const float* __restrict__ Wdt, const float* __restrict__ bdt, float* __restrict__ delta)
{
    int d = threadIdx.x;
    int tok0 = blockIdx.x * 16;
    f4 w0 = *(const f4*)(Wdt + d*8);
    f4 w1 = *(const f4*)(Wdt + d*8 + 4);
    float bias = bdt[d];
    __shared__ float dts[16][8];
    if (threadIdx.x < 128){
        int ti = threadIdx.x >> 3, r = threadIdx.x & 7;
        dts[ti][r] = dt_c[(size_t)(tok0+ti)*8 + r];
    }
    __syncthreads();
    #pragma unroll 4
    for (int ti=0; ti<16; ++ti){
        f4 d0 = *(const f4*)&dts[ti][0];
        f4 d1 = *(const f4*)&dts[ti][4];
        float v = bias;
        v = fmaf(d0.x,w0.x, v); v = fmaf(d0.y,w0.y, v);
        v = fmaf(d0.z,w0.z, v); v = fmaf(d0.w,w0.w, v);
        v = fmaf(d1.x,w1.x, v); v = fmaf(d1.y,w1.y, v);
        v = fmaf(d1.z,w1.z, v); v = fmaf(d1.w,w1.w, v);
        float sp = (v > 20.f) ? v : log1pf(__expf(v));
        delta[(size_t)(tok0+ti)*DI + d] = sp;
    }
}

// ---------------- scan pass 1: GRP=4, reg-double-buffered (δ,δu) + 8-deep B prefetch ----------------
__global__ void __launch_bounds__(256,8) k_scan1(const float* __restrict__ delta,
    const float* __restrict__ u, const float* __restrict__ bc,
    const float* __restrict__ alog, float* __restrict__ hfin, float* __restrict__ aprod)
{
    __shared__ float2 DDb[4][64];
    int bid = blockIdx.x;
    int b = bid & 7;
    int i = bid >> 3;          // 0..191
    int g = i % 3;             // groups 0..2 (last group's state never needed)
    int dblk = i / 3;          // 0..63
    int wave = threadIdx.x >> 6, lane = threadIdx.x & 63;
    int d = dblk*4 + wave;
    int tok0 = b*LSEQ + g*GLEN;
    const float* dptr = delta + (size_t)tok0*DI + d;
    const float* uptr = u     + (size_t)tok0*DI + d;
    float Acoef = -__expf(alog[d*DSN + lane]) * 1.44269504f;
    float h = 0.f, cum = 0.f;
    float2* DDw = DDb[wave];
    float Bpf[8];
    {
        const float* bp = bc + (size_t)tok0*128 + lane;
        #pragma unroll
        for (int k8=0;k8<8;++k8) Bpf[k8] = bp[k8*128];
    }
    const float* bpn = bc + (size_t)(tok0+8)*128 + lane;   // prefetch base, 8 rows ahead
    float dvr = dptr[(size_t)lane*DI];
    float uvr = uptr[(size_t)lane*DI];

    for (int c=0;c<GLEN/64;++c){
        float dv = dvr, uv = uvr;
        if (c+1 < GLEN/64){
            size_t o = (size_t)((c+1)*64+lane)*DI;
            dvr = dptr[o]; uvr = uptr[o];
        }
        float duv = dv*uv;
        DDw[lane] = (float2){dv, duv};
        float cs = dv;
        #pragma unroll
        for (int off=32; off; off>>=1) cs += __shfl_xor(cs, off);
        cum += cs;
        float2 spA[4], spB[4];
        #pragma unroll
        for (int k=0;k<4;++k) spA[k] = DDw[k];
        #pragma unroll 1
        for (int m2=0;m2<4;++m2){
            int base = m2*16;
            int basew = (base+16)&63;
            #pragma unroll
            for (int k=0;k<4;++k){           // steps base+0..3, slots 0..3
                spB[k] = DDw[base+4+k];
                float Bn = Bpf[k];
                Bpf[k] = bpn[k*128];
                float2 sp = spA[k];
                h = fmaf(EXP2(Acoef*sp.x), h, sp.y*Bn);
            }
            #pragma unroll
            for (int k=0;k<4;++k){           // steps base+4..7, slots 4..7
                spA[k] = DDw[base+8+k];
                float Bn = Bpf[4+k];
                Bpf[4+k] = bpn[(4+k)*128];
                float2 sp = spB[k];
                h = fmaf(EXP2(Acoef*sp.x), h, sp.y*Bn);
            }
            bpn += 8*128;
            #pragma unroll
            for (int k=0;k<4;++k){           // steps base+8..11, slots 0..3
                spB[k] = DDw[base+12+k];
                float Bn = Bpf[k];
                Bpf[k] = bpn[k*128];
                float2 sp = spA[k];
                h = fmaf(EXP2(Acoef*sp.x), h, sp.y*Bn);
            }
            #pragma unroll
            for (int k=0;k<4;++k){           // steps base+12..15, slots 4..7
                spA[k] = DDw[basew+k];
                float Bn = Bpf[4+k];
                Bpf[4+k] = bpn[(4+k)*128];
                float2 sp = spB[k];
                h = fmaf(EXP2(Acoef*sp.x), h, sp.y*Bn);
            }
            bpn += 8*128;
        }
    }
    size_t idx = ((size_t)(b*DI + d)*GRP + g)*DSN + lane;
    hfin[idx]  = h;
    aprod[idx] = EXP2(Acoef*cum);
}

// ---------------- scan combine ----------------
__global__ void __launch_bounds__(256) k_comb(const float* __restrict__ hfin,
    const float* __restrict__ aprod, float* __restrict__ hin)
{
    int bd = blockIdx.x*4 + (threadIdx.x>>6);
    int lane = threadIdx.x & 63;
    size_t base = (size_t)bd*GRP*DSN + lane;
    float h = 0.f;
    hin[base] = 0.f;
    #pragma unroll
    for (int g=0; g<GRP-1; ++g){
        float hf = hfin[base + (size_t)g*DSN];
        float ap = aprod[base + (size_t)g*DSN];
        h = fmaf(ap, h, hf);
        hin[base + (size_t)(g+1)*DSN] = h;
    }
}

// ---------------- scan pass 2: GRP=4, reg-double-buffered (δ,δu) + 8-deep B/C prefetch ----------------
__global__ void __launch_bounds__(256,8) k_scan2(const float* __restrict__ delta,
    const float* __restrict__ u, const float* __restrict__ bc,
    const float* __restrict__ alog, const float* __restrict__ Dp,
    const float* __restrict__ hin, float* __restrict__ ygT)
{
    __shared__ float Q[4][64][17];
    __shared__ float2 DDb[4][64];
    int bid = blockIdx.x;
    int b = bid & 7;
    int i = bid >> 3;          // 0..255
    int g = i & 3;
    int dblk = i >> 2;         // 0..63
    int wave = threadIdx.x >> 6, lane = threadIdx.x & 63;
    int d = dblk*4 + wave;
    int bd = b*DI + d;
    int tok0 = b*LSEQ + g*GLEN;
    float Acoef = -__expf(alog[d*DSN + lane]) * 1.44269504f;
    float Dd = Dp[d];
    float h = hin[((size_t)bd*GRP + g)*DSN + lane];
    const float* dptr = delta + (size_t)tok0*DI + d;
    const float* uptr = u     + (size_t)tok0*DI + d;
    float* yout = ygT + (size_t)bd*LSEQ + g*GLEN;
    float (*Qw)[17] = Q[wave];
    float2* DDw = DDb[wave];
    int q16 = (lane>>4)*16;
    int cidx = lane & 15;
    float Bpf[8], Cpf[8];
    {
        const float* bp = bc + (size_t)tok0*128 + lane;
        #pragma unroll
        for (int k8=0;k8<8;++k8){ Bpf[k8] = bp[k8*128]; Cpf[k8] = bp[k8*128 + 64]; }
    }
    const float* bpn = bc + (size_t)(tok0+8)*128 + lane;   // prefetch base, 8 rows ahead
    float dvr = dptr[(size_t)lane*DI];
    float uvr = uptr[(size_t)lane*DI];

    for (int c=0;c<GLEN/64;++c){
        float dv = dvr, uv = uvr;
        if (c+1 < GLEN/64){
            size_t o = (size_t)((c+1)*64+lane)*DI;
            dvr = dptr[o]; uvr = uptr[o];
        }
        float duv = dv*uv;
        DDw[lane] = (float2){dv, duv};     // wave-private; same-wave ds ordering via lgkmcnt
        float2 spA[4], spB[4];
        #pragma unroll
        for (int k=0;k<4;++k) spA[k] = DDw[k];
        float y = 0.f;
        #pragma unroll 1
        for (int m2=0;m2<4;++m2){
            int base = m2*16;
            int basew = (base+16)&63;
            #pragma unroll
            for (int k=0;k<4;++k){           // steps base+0..3, slots 0..3, Q 0..3
                spB[k] = DDw[base+4+k];
                float Bn = Bpf[k], Cn = Cpf[k];
                Bpf[k] = bpn[k*128];
                Cpf[k] = bpn[k*128 + 64];
                float2 sp = spA[k];
                float a = EXP2(Acoef*sp.x);
                h = fmaf(a, h, sp.y*Bn);
                Qw[lane][k] = h*Cn;
            }
            #pragma unroll
            for (int k=0;k<4;++k){           // steps base+4..7, slots 4..7, Q 4..7
                spA[k] = DDw[base+8+k];
                float Bn = Bpf[4+k], Cn = Cpf[4+k];
                Bpf[4+k] = bpn[(4+k)*128];
                Cpf[4+k] = bpn[(4+k)*128 + 64];
                float2 sp = spB[k];
                float a = EXP2(Acoef*sp.x);
                h = fmaf(a, h, sp.y*Bn);
                Qw[lane][4+k] = h*Cn;
            }
            bpn += 8*128;
            #pragma unroll
            for (int k=0;k<4;++k){           // steps base+8..11, slots 0..3, Q 8..11
                spB[k] = DDw[base+12+k];
                float Bn = Bpf[k], Cn = Cpf[k];
                Bpf[k] = bpn[k*128];
                Cpf[k] = bpn[k*128 + 64];
                float2 sp = spA[k];
                float a = EXP2(Acoef*sp.x);
                h = fmaf(a, h, sp.y*Bn);
                Qw[lane][8+k] = h*Cn;
            }
            #pragma unroll
            for (int k=0;k<4;++k){           // steps base+12..15, slots 4..7, Q 12..15
                spA[k] = DDw[basew+k];
                float Bn = Bpf[4+k], Cn = Cpf[4+k];
                Bpf[4+k] = bpn[(4+k)*128];
                Cpf[4+k] = bpn[(4+k)*128 + 64];
                float2 sp = spB[k];
                float a = EXP2(Acoef*sp.x);
                h = fmaf(a, h, sp.y*Bn);
                Qw[lane][12+k] = h*Cn;
            }
            bpn += 8*128;
            float r = 0.f;
            #pragma unroll
            for (int ii=0;ii<16;++ii) r += Qw[q16+ii][cidx];
            r += __shfl_xor(r, 16);
            r += __shfl_xor(r, 32);
            y = ((lane>>4)==m2) ? r : y;
        }
        yout[c*64 + lane] = fmaf(uv, Dd, y);
    }
}

extern "C" void kernel_launch(void* const* d_in, const int* in_sizes, int n_in,
                              void* d_out, int out_size, void* d_ws, size_t ws_size,
                              hipStream_t stream)
{
    (void)in_sizes; (void)n_in; (void)out_size; (void)ws_size;
    const float* x    = (const float*)d_in[0];
    const float* nw   = (const float*)d_in[1];
    const float* nb   = (const float*)d_in[2];
    const float* w_in = (const float*)d_in[3];
    const float* cw   = (const float*)d_in[4];
    const float* cb   = (const float*)d_in[5];
    const float* wx   = (const float*)d_in[6];
    const float* wdt  = (const float*)d_in[7];
    const float* bdt  = (const float*)d_in[8];
    const float* alog = (const float*)d_in[9];
    const float* Dp   = (const float*)d_in[10];
    const float* wo   = (const float*)d_in[11];
    float* out = (float*)d_out;

    float* ws    = (float*)d_ws;
    float* xu    = ws;                                  // NTOK*256 (u pre-conv, fp32)
    float* u     = xu    + (size_t)NTOK*DI;             // NTOK*256
    float* bcp   = u     + (size_t)NTOK*DI;             // NTOK*128 (B at 0..63, C at 64..127)
    float* dt_c  = bcp   + (size_t)NTOK*128 + 2048;     // NTOK*8  (+slack for bc prefetch over-read)
    float* delta = dt_c  + (size_t)NTOK*8;              // NTOK*256
    float* ygT   = delta + (size_t)NTOK*DI;             // NTOK*256
    float* stats = ygT   + (size_t)NTOK*DI;             // NTOK*2
    float* hfin  = stats + (size_t)NTOK*2;
    float* aprod = hfin  + (size_t)NB*DI*GRP*DSN;
    float* hin   = aprod + (size_t)NB*DI*GRP*DSN;
    unsigned short* zbf  = (unsigned short*)(hin + (size_t)NB*DI*GRP*DSN); // NTOK*256 bf16
    unsigned short* ygbf = zbf + (size_t)NTOK*DI;                          // NTOK*256 bf16

    k_lnstats<<<NTOK/4, 256, 0, stream>>>(x, stats);

    dim3 g1(NTOK/128, 512/64);
    k_gemm_bf<512,128,0><<<g1, 256, 0, stream>>>(x, nullptr, w_in, xu, nullptr, zbf, 0, stats, nw, nb, nullptr);

    k_conv<<<NTOK*64/256, 256, 0, stream>>>(xu, cw, cb, u);

    dim3 g2(NTOK/128, 3);
    k_gemm_bf<136,256,1><<<g2, 256, 0, stream>>>(u, nullptr, wx, bcp, dt_c, nullptr, 0, nullptr, nullptr, nullptr, nullptr);

    k_delta<<<NTOK/16, 256, 0, stream>>>(dt_c, wdt, bdt, delta);

    k_scan1<<<NB*(GRP-1)*64, 256, 0, stream>>>(delta, u, bcp, alog, hfin, aprod);
    k_comb<<<NB*DI/4, 256, 0, stream>>>(hfin, aprod, hin);
    k_scan2<<<NB*GRP*64, 256, 0, stream>>>(delta, u, bcp, alog, Dp, hin, ygT);

    dim3 gt(LSEQ/64, NB*4);
    k_trans<<<gt, 256, 0, stream>>>(ygT, zbf, ygbf);

    dim3 g3(NTOK/128, 2);
    k_gemm_bf<128,256,2><<<g3, 256, 0, stream>>>(nullptr, ygbf, wo, out, nullptr, nullptr, 128, nullptr, nullptr, nullptr, x);
}

// Round 17
// 436.689 us; speedup vs baseline: 1.0668x; 1.0668x over previous
//
#include <hip/hip_runtime.h>
#include <math.h>

#define DM 128
#define DI 256
#define DSN 64
#define NB 8
#define LSEQ 4096
#define NTOK (NB*LSEQ)
#define GRP 4
#define GLEN (LSEQ/GRP)   // 1024

typedef float4 f4;
typedef __attribute__((ext_vector_type(8))) short bf16x8;
typedef __attribute__((ext_vector_type(4))) float f32x4;
typedef __attribute__((ext_vector_type(8))) unsigned short us8;

#if __has_builtin(__builtin_amdgcn_exp2f)
#define EXP2(x) __builtin_amdgcn_exp2f(x)
#else
#define EXP2(x) __expf((x)*0.6931471805599453f)
#endif

__device__ __forceinline__ float sigmoidf_(float x){ return 1.f/(1.f+__expf(-x)); }
__device__ __forceinline__ unsigned short f2bf(float f){
    unsigned u = __float_as_uint(f);
    unsigned r = u + 0x7FFFu + ((u>>16)&1u);   // RNE
    return (unsigned short)(r>>16);
}
__device__ __forceinline__ float bf2f(unsigned short s){
    return __uint_as_float(((unsigned)s)<<16);
}

// ---------------- LayerNorm stats (mu, rstd) per token ----------------
__global__ void __launch_bounds__(256) k_lnstats(const float* __restrict__ x, float* __restrict__ stats){
    int tok = blockIdx.x*4 + (threadIdx.x>>6);
    int lane = threadIdx.x & 63;
    const float* row = x + (size_t)tok*DM;
    float a = row[lane], b = row[lane+64];
    float s = a+b, ss = a*a+b*b;
    #pragma unroll
    for (int off=32; off>0; off>>=1){ s += __shfl_xor(s,off); ss += __shfl_xor(ss,off); }
    if (lane==0){
        float mu = s*(1.f/128.f);
        float var = ss*(1.f/128.f) - mu*mu;
        stats[tok*2+0] = mu;
        stats[tok*2+1] = rsqrtf(var + 1e-6f);
    }
}

// ---------------- bf16 MFMA GEMM: C[M][N] = A[M][K] * Bw[N][K]^T ----------------
// MODE 0: A = LN(x) on the fly; epilogue: col<256 -> Cout (xu fp32), col>=256 -> Zout (zbf bf16)
// MODE 1: A = fp32 row-major (x_proj); col<8 -> Cout2 (dt), cols 8..135 -> Cout (bc pack)
// MODE 2: A = bf16 row-major (out_proj, A=ygbf) + residual
template<int N_DIM,int K_DIM,int MODE>
__global__ void __launch_bounds__(256) k_gemm_bf(const float* __restrict__ Af32,
    const unsigned short* __restrict__ Abf, const float* __restrict__ Bw,
    float* __restrict__ Cout, float* __restrict__ Cout2, unsigned short* __restrict__ Zout,
    int ldC, const float* __restrict__ stats, const float* __restrict__ nw,
    const float* __restrict__ nb, const float* __restrict__ resid)
{
    __shared__ unsigned short Abuf[128*72];
    __shared__ unsigned short Bbuf[64*72];
    const int tid = threadIdx.x;
    const int m0 = blockIdx.x*128;
    const int n0 = blockIdx.y*64;
    const int wave = tid>>6, lane = tid&63;
    const int wm = wave>>1, wn = wave&1;
    const int lr = lane&15, lk = (lane>>4)*8;
    f32x4 acc[4][2];
    #pragma unroll
    for (int i=0;i<4;++i){
        #pragma unroll
        for (int j=0;j<2;++j) acc[i][j] = (f32x4){0.f,0.f,0.f,0.f};
    }

    for (int k0=0; k0<K_DIM; k0+=64){
        {
            int row = tid>>1, ks = (tid&1)*32;
            int m = m0 + row;
            unsigned short* dst = &Abuf[row*72 + ks];
            if (MODE==2){
                const unsigned short* src = Abf + (size_t)m*K_DIM + k0 + ks;
                #pragma unroll
                for (int q=0;q<4;++q) *(us8*)(dst+q*8) = *(const us8*)(src+q*8);
            } else {
                const float* src = Af32 + (size_t)m*K_DIM + k0 + ks;
                float mu=0.f, rs=1.f;
                if (MODE==0){ mu = stats[2*m]; rs = stats[2*m+1]; }
                #pragma unroll
                for (int q=0;q<4;++q){
                    f4 v0 = *(const f4*)(src+q*8);
                    f4 v1 = *(const f4*)(src+q*8+4);
                    if (MODE==0){
                        int kk = k0+ks+q*8;
                        f4 w0=*(const f4*)(nw+kk), w1=*(const f4*)(nw+kk+4);
                        f4 c0=*(const f4*)(nb+kk), c1=*(const f4*)(nb+kk+4);
                        v0.x=(v0.x-mu)*rs*w0.x+c0.x; v0.y=(v0.y-mu)*rs*w0.y+c0.y;
                        v0.z=(v0.z-mu)*rs*w0.z+c0.z; v0.w=(v0.w-mu)*rs*w0.w+c0.w;
                        v1.x=(v1.x-mu)*rs*w1.x+c1.x; v1.y=(v1.y-mu)*rs*w1.y+c1.y;
                        v1.z=(v1.z-mu)*rs*w1.z+c1.z; v1.w=(v1.w-mu)*rs*w1.w+c1.w;
                    }
                    us8 o = {f2bf(v0.x),f2bf(v0.y),f2bf(v0.z),f2bf(v0.w),
                             f2bf(v1.x),f2bf(v1.y),f2bf(v1.z),f2bf(v1.w)};
                    *(us8*)(dst+q*8) = o;
                }
            }
        }
        {
            int row = tid>>2, ks = (tid&3)*16;
            int n = n0 + row;
            unsigned short* dst = &Bbuf[row*72 + ks];
            #pragma unroll
            for (int q=0;q<2;++q){
                f4 v0={0.f,0.f,0.f,0.f}, v1={0.f,0.f,0.f,0.f};
                if (N_DIM%64==0 || n < N_DIM){
                    const float* src = Bw + (size_t)n*K_DIM + k0 + ks + q*8;
                    v0 = *(const f4*)src; v1 = *(const f4*)(src+4);
                }
                us8 o = {f2bf(v0.x),f2bf(v0.y),f2bf(v0.z),f2bf(v0.w),
                         f2bf(v1.x),f2bf(v1.y),f2bf(v1.z),f2bf(v1.w)};
                *(us8*)(dst+q*8) = o;
            }
        }
        __syncthreads();
        #pragma unroll
        for (int kk=0; kk<64; kk+=32){
            bf16x8 bfr[2], afr[4];
            #pragma unroll
            for (int fn=0;fn<2;++fn)
                bfr[fn] = *(const bf16x8*)&Bbuf[(wn*32+fn*16+lr)*72 + kk + lk];
            #pragma unroll
            for (int fm=0;fm<4;++fm)
                afr[fm] = *(const bf16x8*)&Abuf[(wm*64+fm*16+lr)*72 + kk + lk];
            #pragma unroll
            for (int fm=0;fm<4;++fm){
                #pragma unroll
                for (int fn=0;fn<2;++fn)
                    acc[fm][fn] = __builtin_amdgcn_mfma_f32_16x16x32_bf16(afr[fm], bfr[fn], acc[fm][fn], 0,0,0);
            }
        }
        __syncthreads();
    }
    const int cb = (lane>>4)*4;
    #pragma unroll
    for (int fm=0;fm<4;++fm){
        #pragma unroll
        for (int fn=0;fn<2;++fn){
            int col = n0 + wn*32 + fn*16 + lr;
            if (N_DIM%64!=0 && col >= N_DIM) continue;
            #pragma unroll
            for (int r=0;r<4;++r){
                int m = m0 + wm*64 + fm*16 + cb + r;
                float v = acc[fm][fn][r];
                if (MODE==0){
                    if (col < 256) Cout[(size_t)m*256 + col] = v;
                    else           Zout[(size_t)m*256 + (col-256)] = f2bf(v);
                } else if (MODE==1){
                    if (col < 8) Cout2[(size_t)m*8 + col] = v;
                    else         Cout[(size_t)m*128 + (col-8)] = v;
                } else {
                    v += resid[(size_t)m*N_DIM + col];
                    Cout[(size_t)m*ldC + col] = v;
                }
            }
        }
    }
}

// ---------------- transpose + gate: ygbf = bf16( ygT^T * silu(z) ), z in bf16 ----------------
__global__ void __launch_bounds__(256) k_trans(const float* __restrict__ ygT,
    const unsigned short* __restrict__ zbf, unsigned short* __restrict__ ygbf)
{
    __shared__ float T[64][65];
    int t0 = blockIdx.x*64;
    int w  = blockIdx.y;
    int b  = w>>2, d0 = (w&3)*64;
    int tid = threadIdx.x;
    {
        int dl = tid>>2, ts = (tid&3)*16;
        const float* src = ygT + ((size_t)(b*DI + d0 + dl))*LSEQ + t0 + ts;
        #pragma unroll
        for (int q=0;q<4;++q) *(f4*)&T[dl][ts+q*4] = *(const f4*)(src+q*4);
    }
    __syncthreads();
    {
        int tl = tid>>2, ds8 = (tid&3)*16;
        size_t tok = (size_t)(b*LSEQ + t0 + tl);
        const unsigned short* zsrc = zbf + tok*DI + d0 + ds8;
        unsigned short* dst = ygbf + tok*DI + d0 + ds8;
        us8 zv0 = *(const us8*)zsrc;
        us8 zv1 = *(const us8*)(zsrc+8);
        us8 o0, o1;
        #pragma unroll
        for (int j=0;j<8;++j){
            float z0 = bf2f(zv0[j]);
            float z1 = bf2f(zv1[j]);
            float g0 = z0 * sigmoidf_(z0);
            float g1 = z1 * sigmoidf_(z1);
            o0[j] = f2bf(T[ds8+j][tl]   * g0);
            o1[j] = f2bf(T[ds8+8+j][tl] * g1);
        }
        *(us8*)dst = o0; *(us8*)(dst+8) = o1;
    }
}

// ---------------- causal depthwise conv (k=4) + SiLU (reads compact xu) ----------------
__global__ void __launch_bounds__(256) k_conv(const float* __restrict__ xu,
    const float* __restrict__ cw, const float* __restrict__ cb, float* __restrict__ u)
{
    int idx = blockIdx.x*256 + threadIdx.x;
    int dq = idx & 63;
    int tok = idx >> 6;
    int t = tok & (LSEQ-1);
    f4 w0 = *(const f4*)(cw + (dq*4+0)*4);
    f4 w1 = *(const f4*)(cw + (dq*4+1)*4);
    f4 w2 = *(const f4*)(cw + (dq*4+2)*4);
    f4 w3 = *(const f4*)(cw + (dq*4+3)*4);
    f4 r  = *(const f4*)(cb + dq*4);
    #pragma unroll
    for (int j=0;j<4;++j){
        int tj = t-3+j;
        if (tj < 0) continue;
        f4 v = *(const f4*)(xu + (size_t)(tok-3+j)*DI + dq*4);
        r.x = fmaf(v.x, ((const float*)&w0)[j], r.x);
        r.y = fmaf(v.y, ((const float*)&w1)[j], r.y);
        r.z = fmaf(v.z, ((const float*)&w2)[j], r.z);
        r.w = fmaf(v.w, ((const float*)&w3)[j], r.w);
    }
    r.x *= sigmoidf_(r.x); r.y *= sigmoidf_(r.y);
    r.z *= sigmoidf_(r.z); r.w *= sigmoidf_(r.w);
    *(f4*)(u + (size_t)tok*DI + dq*4) = r;
}

// ---------------- delta = softplus(dt @ Wdt^T + bdt) ----------------
__global__ void __launch_bounds__(256) k_delta(const float* __restrict__ dt_c,
    const float* __restrict__ Wdt, const float* __restrict__ bdt, float* __restrict__ delta)
{
    int d = threadIdx.x;
    int tok0 = blockIdx.x * 16;
    f4 w0 = *(const f4*)(Wdt + d*8);
    f4 w1 = *(const f4*)(Wdt + d*8 + 4);
    float bias = bdt[d];
    __shared__ float dts[16][8];
    if (threadIdx.x < 128){
        int ti = threadIdx.x >> 3, r = threadIdx.x & 7;
        dts[ti][r] = dt_c[(size_t)(tok0+ti)*8 + r];
    }
    __syncthreads();
    #pragma unroll 4
    for (int ti=0; ti<16; ++ti){
        f4 d0 = *(const f4*)&dts[ti][0];
        f4 d1 = *(const f4*)&dts[ti][4];
        float v = bias;
        v = fmaf(d0.x,w0.x, v); v = fmaf(d0.y,w0.y, v);
        v = fmaf(d0.z,w0.z, v); v = fmaf(d0.w,w0.w, v);
        v = fmaf(d1.x,w1.x, v); v = fmaf(d1.y,w1.y, v);
        v = fmaf(d1.z,w1.z, v); v = fmaf(d1.w,w1.w, v);
        float sp = (v > 20.f) ? v : log1pf(__expf(v));
        delta[(size_t)(tok0+ti)*DI + d] = sp;
    }
}

// ---------------- scan pass 1: GRP=4, LDS broadcast + 8-deep B prefetch + chunk-ahead dv/uv ----------------
__global__ void __launch_bounds__(256,8) k_scan1(const float* __restrict__ delta,
    const float* __restrict__ u, const float* __restrict__ bc,
    const float* __restrict__ alog, float* __restrict__ hfin, float* __restrict__ aprod)
{
    __shared__ float2 DDb[4][64];
    int bid = blockIdx.x;
    int b = bid & 7;
    int i = bid >> 3;          // 0..191
    int g = i % 3;             // groups 0..2 (last group's state never needed)
    int dblk = i / 3;          // 0..63
    int wave = threadIdx.x >> 6, lane = threadIdx.x & 63;
    int d = dblk*4 + wave;
    int tok0 = b*LSEQ + g*GLEN;
    const float* dptr = delta + (size_t)tok0*DI + d;
    const float* uptr = u     + (size_t)tok0*DI + d;
    float Acoef = -__expf(alog[d*DSN + lane]) * 1.44269504f;
    float h = 0.f, cum = 0.f;
    float2* DDw = DDb[wave];
    float Bpf[8];
    {
        const float* bp = bc + (size_t)tok0*128 + lane;
        #pragma unroll
        for (int k8=0;k8<8;++k8) Bpf[k8] = bp[k8*128];
    }
    const float* bpn = bc + (size_t)(tok0+8)*128 + lane;   // prefetch base, 8 rows ahead
    float dvr = dptr[(size_t)lane*DI];
    float uvr = uptr[(size_t)lane*DI];

    for (int c=0;c<GLEN/64;++c){
        float dv = dvr, uv = uvr;
        if (c+1 < GLEN/64){
            size_t o = (size_t)((c+1)*64+lane)*DI;
            dvr = dptr[o]; uvr = uptr[o];
        }
        float duv = dv*uv;
        DDw[lane] = (float2){dv, duv};     // wave-private broadcast buffer
        float cs = dv;
        #pragma unroll
        for (int off=32; off; off>>=1) cs += __shfl_xor(cs, off);
        cum += cs;
        #pragma unroll 1
        for (int g8=0;g8<8;++g8){
            #pragma unroll
            for (int k8=0;k8<8;++k8){
                int j = g8*8 + k8;
                float Bn = Bpf[k8];
                Bpf[k8] = bpn[k8*128];
                float2 sp = DDw[j];        // uniform addr -> LDS broadcast
                float a = EXP2(Acoef*sp.x);
                h = fmaf(a, h, sp.y*Bn);
            }
            bpn += 8*128;
        }
    }
    size_t idx = ((size_t)(b*DI + d)*GRP + g)*DSN + lane;
    hfin[idx]  = h;
    aprod[idx] = EXP2(Acoef*cum);
}

// ---------------- scan combine ----------------
__global__ void __launch_bounds__(256) k_comb(const float* __restrict__ hfin,
    const float* __restrict__ aprod, float* __restrict__ hin)
{
    int bd = blockIdx.x*4 + (threadIdx.x>>6);
    int lane = threadIdx.x & 63;
    size_t base = (size_t)bd*GRP*DSN + lane;
    float h = 0.f;
    hin[base] = 0.f;
    #pragma unroll
    for (int g=0; g<GRP-1; ++g){
        float hf = hfin[base + (size_t)g*DSN];
        float ap = aprod[base + (size_t)g*DSN];
        h = fmaf(ap, h, hf);
        hin[base + (size_t)(g+1)*DSN] = h;
    }
}

// ---------------- scan pass 2: GRP=4, LDS broadcast + 8-deep B/C prefetch + chunk-ahead dv/uv ----------------
__global__ void __launch_bounds__(256,8) k_scan2(const float* __restrict__ delta,
    const float* __restrict__ u, const float* __restrict__ bc,
    const float* __restrict__ alog, const float* __restrict__ Dp,
    const float* __restrict__ hin, float* __restrict__ ygT)
{
    __shared__ float Q[4][64][17];
    __shared__ float2 DDb[4][64];
    int bid = blockIdx.x;
    int b = bid & 7;
    int i = bid >> 3;          // 0..255
    int g = i & 3;
    int dblk = i >> 2;         // 0..63
    int wave = threadIdx.x >> 6, lane = threadIdx.x & 63;
    int d = dblk*4 + wave;
    int bd = b*DI + d;
    int tok0 = b*LSEQ + g*GLEN;
    float Acoef = -__expf(alog[d*DSN + lane]) * 1.44269504f;
    float Dd = Dp[d];
    float h = hin[((size_t)bd*GRP + g)*DSN + lane];
    const float* dptr = delta + (size_t)tok0*DI + d;
    const float* uptr = u     + (size_t)tok0*DI + d;
    float* yout = ygT + (size_t)bd*LSEQ + g*GLEN;
    float (*Qw)[17] = Q[wave];
    float2* DDw = DDb[wave];
    int q16 = (lane>>4)*16;
    int cidx = lane & 15;
    float Bpf[8], Cpf[8];
    {
        const float* bp = bc + (size_t)tok0*128 + lane;
        #pragma unroll
        for (int k8=0;k8<8;++k8){ Bpf[k8] = bp[k8*128]; Cpf[k8] = bp[k8*128 + 64]; }
    }
    const float* bpn = bc + (size_t)(tok0+8)*128 + lane;   // prefetch base, 8 rows ahead
    float dvr = dptr[(size_t)lane*DI];
    float uvr = uptr[(size_t)lane*DI];

    for (int c=0;c<GLEN/64;++c){
        float dv = dvr, uv = uvr;
        if (c+1 < GLEN/64){
            size_t o = (size_t)((c+1)*64+lane)*DI;
            dvr = dptr[o]; uvr = uptr[o];
        }
        float duv = dv*uv;
        DDw[lane] = (float2){dv, duv};     // wave-private; same-wave ds ordering via lgkmcnt
        float y = 0.f;
        #pragma unroll 1
        for (int m2=0;m2<4;++m2){
            #pragma unroll 1
            for (int half=0; half<2; ++half){
                #pragma unroll
                for (int k8=0;k8<8;++k8){
                    int j = m2*16 + half*8 + k8;
                    float Bn = Bpf[k8], Cn = Cpf[k8];
                    Bpf[k8] = bpn[k8*128];
                    Cpf[k8] = bpn[k8*128 + 64];
                    float2 sp = DDw[j];            // uniform addr -> LDS broadcast
                    float a = EXP2(Acoef*sp.x);
                    h = fmaf(a, h, sp.y*Bn);
                    Qw[lane][half*8+k8] = h*Cn;
                }
                bpn += 8*128;
            }
            float r = 0.f;
            #pragma unroll
            for (int ii=0;ii<16;++ii) r += Qw[q16+ii][cidx];
            r += __shfl_xor(r, 16);
            r += __shfl_xor(r, 32);
            y = ((lane>>4)==m2) ? r : y;
        }
        yout[c*64 + lane] = fmaf(uv, Dd, y);
    }
}

extern "C" void kernel_launch(void* const* d_in, const int* in_sizes, int n_in,
                              void* d_out, int out_size, void* d_ws, size_t ws_size,
                              hipStream_t stream)
{
    (void)in_sizes; (void)n_in; (void)out_size; (void)ws_size;
    const float* x    = (const float*)d_in[0];
    const float* nw   = (const float*)d_in[1];
    const float* nb   = (const float*)d_in[2];
    const float* w_in = (const float*)d_in[3];
    const float* cw   = (const float*)d_in[4];
    const float* cb   = (const float*)d_in[5];
    const float* wx   = (const float*)d_in[6];
    const float* wdt  = (const float*)d_in[7];
    const float* bdt  = (const float*)d_in[8];
    const float* alog = (const float*)d_in[9];
    const float* Dp   = (const float*)d_in[10];
    const float* wo   = (const float*)d_in[11];
    float* out = (float*)d_out;

    float* ws    = (float*)d_ws;
    float* xu    = ws;                                  // NTOK*256 (u pre-conv, fp32)
    float* u     = xu    + (size_t)NTOK*DI;             // NTOK*256
    float* bcp   = u     + (size_t)NTOK*DI;             // NTOK*128 (B at 0..63, C at 64..127)
    float* dt_c  = bcp   + (size_t)NTOK*128 + 2048;     // NTOK*8  (+slack for bc prefetch over-read)
    float* delta = dt_c  + (size_t)NTOK*8;              // NTOK*256
    float* ygT   = delta + (size_t)NTOK*DI;             // NTOK*256
    float* stats = ygT   + (size_t)NTOK*DI;             // NTOK*2
    float* hfin  = stats + (size_t)NTOK*2;
    float* aprod = hfin  + (size_t)NB*DI*GRP*DSN;
    float* hin   = aprod + (size_t)NB*DI*GRP*DSN;
    unsigned short* zbf  = (unsigned short*)(hin + (size_t)NB*DI*GRP*DSN); // NTOK*256 bf16
    unsigned short* ygbf = zbf + (size_t)NTOK*DI;                          // NTOK*256 bf16

    k_lnstats<<<NTOK/4, 256, 0, stream>>>(x, stats);

    dim3 g1(NTOK/128, 512/64);
    k_gemm_bf<512,128,0><<<g1, 256, 0, stream>>>(x, nullptr, w_in, xu, nullptr, zbf, 0, stats, nw, nb, nullptr);

    k_conv<<<NTOK*64/256, 256, 0, stream>>>(xu, cw, cb, u);

    dim3 g2(NTOK/128, 3);
    k_gemm_bf<136,256,1><<<g2, 256, 0, stream>>>(u, nullptr, wx, bcp, dt_c, nullptr, 0, nullptr, nullptr, nullptr, nullptr);

    k_delta<<<NTOK/16, 256, 0, stream>>>(dt_c, wdt, bdt, delta);

    k_scan1<<<NB*(GRP-1)*64, 256, 0, stream>>>(delta, u, bcp, alog, hfin, aprod);
    k_comb<<<NB*DI/4, 256, 0, stream>>>(hfin, aprod, hin);
    k_scan2<<<NB*GRP*64, 256, 0, stream>>>(delta, u, bcp, alog, Dp, hin, ygT);

    dim3 gt(LSEQ/64, NB*4);
    k_trans<<<gt, 256, 0, stream>>>(ygT, zbf, ygbf);

    dim3 g3(NTOK/128, 2);
    k_gemm_bf<128,256,2><<<g3, 256, 0, stream>>>(nullptr, ygbf, wo, out, nullptr, nullptr, 128, nullptr, nullptr, nullptr, x);
}